// Round 5
// baseline (865.178 us; speedup 1.0000x reference)
//
#include <hip/hip_runtime.h>
#include <math.h>

#ifndef M_PI
#define M_PI 3.14159265358979323846
#endif

#define NBLK 512   // 512 blocks x 512 thr, __launch_bounds__(512,4) -> 2 blocks/CU -> all co-resident

// B=64, C=3, H=W=512.
// Loss = mean_b | mean_hf(log10 PSD(gen_b)) - mean_hf(log10 PSD(tgt_b)) |
// hf region (unshifted freq): element EXCLUDED iff ky and kx both in [0,64)u[448,512).
// count = 512^2 - 128^2 = 245760.
//
// Single persistent kernel: 4 chunks x 16 images; per chunk: row phase (grayscale+pack+
// row FFT -> transposed scratch), grid barrier, col phase (col FFT + Hermitian split +
// masked log10-PSD reduce -> fp64 atomics). Double-buffered 32MB scratch (L3-resident)
// makes rows(c+1) race-free against cols(c) without a trailing barrier. Finalize in-kernel.
//
// ws: [0,1024) double accum[128]; [1024,1028) unsigned bar; [4096, 4096+64MB) scratch.
// scratch column "col" encodes kx: col(kx) = 64*(kx>>6) + 8*(kx&7) + ((kx>>3)&7)

__device__ __forceinline__ float2 cmulf(float2 a, float2 b) {
    return make_float2(fmaf(a.x, b.x, -(a.y * b.y)), fmaf(a.x, b.y, a.y * b.x));
}
__device__ __forceinline__ float2 caddf(float2 a, float2 b){ return make_float2(a.x+b.x, a.y+b.y); }
__device__ __forceinline__ float2 csubf(float2 a, float2 b){ return make_float2(a.x-b.x, a.y-b.y); }

// natural-order 8-point DFT: v[k] <- sum_a v[a] W_8^{ak}
__device__ __forceinline__ void dft8(float2 v[8]) {
    const float S = 0.70710678118654752440f;
    float2 a0=caddf(v[0],v[4]), a1=caddf(v[1],v[5]), a2=caddf(v[2],v[6]), a3=caddf(v[3],v[7]);
    float2 b0=csubf(v[0],v[4]);
    float2 t1=csubf(v[1],v[5]);
    float2 t2=csubf(v[2],v[6]);
    float2 t3=csubf(v[3],v[7]);
    float2 b1=make_float2(S*(t1.x+t1.y), S*(t1.y-t1.x));   // *(S,-S) = W8^1
    float2 b2=make_float2(t2.y, -t2.x);                    // *(-i)   = W8^2
    float2 b3=make_float2(S*(t3.y-t3.x), -S*(t3.x+t3.y));  // *(-S,-S)= W8^3
    float2 c0=caddf(a0,a2), c1=caddf(a1,a3), c2=csubf(a0,a2);
    float2 u3=csubf(a1,a3); float2 c3=make_float2(u3.y,-u3.x);
    float2 d0=caddf(b0,b2), d1=caddf(b1,b3), d2=csubf(b0,b2);
    float2 w3=csubf(b1,b3); float2 d3=make_float2(w3.y,-w3.x);
    v[0]=caddf(c0,c1); v[4]=csubf(c0,c1);
    v[2]=caddf(c2,c3); v[6]=csubf(c2,c3);
    v[1]=caddf(d0,d1); v[5]=csubf(d0,d1);
    v[3]=caddf(d2,d3); v[7]=csubf(d2,d3);
}

__device__ __forceinline__ void twchain(float2 v[8], float2 w) {
    float2 t = w;
#pragma unroll
    for (int c = 1; c < 8; ++c) {
        v[c] = cmulf(v[c], t);
        if (c < 7) t = cmulf(t, w);
    }
}

// Per-wave 512-pt FFT (512=8*8*8). In: v[a]=x[64a+lane]. Out: lane L, reg e = X[(L>>3)+8*(L&7)+64e].
// wA = W_512^lane, wB = W_512^{8*(lane&7)}. W = wave-private 512-float2 LDS region.
__device__ __forceinline__ void fft512_reg(float2 v[8], float2* __restrict__ W,
                                           float2 wA, float2 wB, int lane) {
    dft8(v);
    twchain(v, wA);
    // T1: rotation swizzle (m + 2c) mod 64 — bijective, bank floor both sides
#pragma unroll
    for (int c = 0; c < 8; ++c) W[(c<<6) + ((lane + 2*c)&63)] = v[c];
    __syncthreads();
    {
        const int c = lane>>3, p = lane&7, base = c<<6, off = p + 2*c;
#pragma unroll
        for (int bb = 0; bb < 8; ++bb) v[bb] = W[base + (((bb<<3) + off)&63)];
    }
    __syncthreads();
    dft8(v);
    twchain(v, wB);
    // T2: XOR swizzle (8d + (p^d) + 2c) mod 64 — bijective, bank floor both sides
    {
        const int c = lane>>3, p = lane&7, base = c<<6, r2 = 2*c;
#pragma unroll
        for (int d = 0; d < 8; ++d) W[base + (((d<<3) + (p^d) + r2)&63)] = v[d];
    }
    __syncthreads();
    {
        const int c = lane>>3, d = lane&7, base = c<<6, off = (d<<3) + 2*c;
#pragma unroll
        for (int p = 0; p < 8; ++p) v[p] = W[base + ((off + (p^d))&63)];
    }
    __syncthreads();
    dft8(v);
}

// Monotonic-counter grid barrier (all NBLK blocks co-resident by construction).
// Explicit agent fences: release prior plain writes (scratch), acquire others' (cross-XCD L2).
__device__ __forceinline__ void grid_barrier(unsigned* bar, unsigned target) {
    __syncthreads();
    if (threadIdx.x == 0) {
        __builtin_amdgcn_fence(__ATOMIC_RELEASE, "agent");
        __hip_atomic_fetch_add(bar, 1u, __ATOMIC_RELAXED, __HIP_MEMORY_SCOPE_AGENT);
        while (__hip_atomic_load(bar, __ATOMIC_RELAXED, __HIP_MEMORY_SCOPE_AGENT) < target)
            __builtin_amdgcn_s_sleep(8);
        __builtin_amdgcn_fence(__ATOMIC_ACQUIRE, "agent");
    }
    __syncthreads();
}

// One (img, rowgroup-of-8) task: 8 waves = 8 rows. scr = chunk scratch slot.
__device__ __forceinline__ void row_task(const float* __restrict__ gen,
        const float* __restrict__ tgt, float2* __restrict__ scr,
        int b, int img_local, int rg, float2* __restrict__ SBUF,
        int tid, int wave, int lane, float2 wA, float2 wB) {
    const int r = (rg<<3) + wave;
    const size_t rowoff = ((size_t)b * 1536 + r) * 512;
    const float* gR = gen + rowoff; const float* gG = gR + 262144; const float* gB = gG + 262144;
    const float* tR = tgt + rowoff; const float* tG = tR + 262144; const float* tB = tG + 262144;

    float2 v[8];
#pragma unroll
    for (int a = 0; a < 8; ++a) {
        const int idx = (a<<6) + lane;
        const float gg = fmaf(0.299f, gR[idx], fmaf(0.587f, gG[idx], fmaf(0.114f, gB[idx], 1.0f))) * 0.5f;
        const float tt = fmaf(0.299f, tR[idx], fmaf(0.587f, tG[idx], fmaf(0.114f, tB[idx], 1.0f))) * 0.5f;
        v[a] = make_float2(gg, tt);        // pack: re=gray01(gen), im=gray01(tgt)
    }
    float2* W = SBUF + (wave<<9);
    fft512_reg(v, W, wA, wB, lane);

    // stage for 64B-contiguous global stores: slot = 512*wave + ((col + 8*wave)&511)
#pragma unroll
    for (int e = 0; e < 8; ++e) {
        const int col = (e<<6) + lane;
        W[(col + (wave<<3)) & 511] = v[e];
    }
    __syncthreads();
    const size_t obase = (size_t)img_local << 18;
    const int r0 = rg<<3;
#pragma unroll
    for (int it = 0; it < 8; ++it) {
        const int col = (tid>>3) + (it<<6);
        const int j = tid&7;
        scr[obase + ((size_t)col<<9) + r0 + j] = SBUF[(j<<9) + ((col + (j<<3)) & 511)];
    }
    __syncthreads();   // protect SBUF reuse by next iteration (cross-wave reads above)
}

// One (img, 4-pair group) task: 8 waves = 4 conjugate kx-pair units of 2 waves.
__device__ __forceinline__ void col_task(const float2* __restrict__ scr,
        double* __restrict__ accum, int b, int img_local, int tq,
        float2* __restrict__ SBUF, double* __restrict__ RED,
        int tid, int wave, int lane, float2 wA, float2 wB) {
    const int unit = wave>>1, w = wave&1;
    const int t = (tq<<2) + unit;                               // pair index 0..255
    const int kx = (t==0) ? (w<<8) : (w ? 512 - t : t);
    const int col = ((kx>>6)<<6) + ((kx&7)<<3) + ((kx>>3)&7);   // col(kx)
    const float2* src = scr + ((size_t)img_local<<18) + ((size_t)col<<9);
    float2 v[8];
#pragma unroll
    for (int a = 0; a < 8; ++a) v[a] = src[(a<<6) + lane];      // coalesced dwordx2

    float2* W = SBUF + (unit<<10) + (w<<9);
    fft512_reg(v, W, wA, wB, lane);

    // publish own spectrum in natural-ky order
    const int cc = lane>>3, dd = lane&7;
#pragma unroll
    for (int e = 0; e < 8; ++e) W[cc + (dd<<3) + (e<<6)] = v[e];
    __syncthreads();

    const float2* pbuf = (t==0) ? W : (SBUF + (unit<<10) + ((1-w)<<9));
    const bool kxin = (kx < 64) || (kx >= 448);

    double sg = 0.0, st = 0.0;
#pragma unroll
    for (int e = 0; e < 8; ++e) {
        const int ky = cc + (dd<<3) + (e<<6);
        if (kxin && ((ky < 64) || (ky >= 448))) continue;       // excluded low-freq box
        const float2 F1 = v[e];
        const float2 F2 = pbuf[(512 - ky) & 511];               // Z[-ky][-kx]
        const float ar = 0.5f*(F1.x + F2.x), ai = 0.5f*(F1.y - F2.y);   // gen
        const float br = 0.5f*(F1.y + F2.y), bi = 0.5f*(F2.x - F1.x);   // tgt
        const float pg = fmaf(ar, ar, ai*ai) + 1e-10f;
        const float pt = fmaf(br, br, bi*bi) + 1e-10f;
        sg += (double)log10f(pg);
        st += (double)log10f(pt);
    }
#pragma unroll
    for (int off = 32; off; off >>= 1) {
        sg += __shfl_down(sg, off);
        st += __shfl_down(st, off);
    }
    if (lane == 0) { RED[wave] = sg; RED[8 + wave] = st; }
    __syncthreads();
    if (tid == 0) {   // block-level reduce: 2 atomics per task instead of 16
        double SG = 0.0, ST = 0.0;
#pragma unroll
        for (int i = 0; i < 8; ++i) { SG += RED[i]; ST += RED[8+i]; }
        atomicAdd(&accum[b], SG);
        atomicAdd(&accum[64 + b], ST);
    }
}

__global__ __launch_bounds__(512, 4)
void hfs_fused(const float* __restrict__ gen, const float* __restrict__ tgt,
               float2* __restrict__ scratch, double* __restrict__ accum,
               unsigned* __restrict__ bar, float* __restrict__ out) {
    __shared__ float2 SBUF[8 * 512];   // 32 KB
    __shared__ double RED[16];
    const int tid = threadIdx.x, wave = tid>>6, lane = tid&63;

    // per-lane twiddles from f64 (once per launch)
    const double aA = -2.0 * M_PI * (double)lane / 512.0;
    const double aB = -2.0 * M_PI * (double)((lane&7)<<3) / 512.0;
    const float2 wA = make_float2((float)cos(aA), (float)sin(aA));
    const float2 wB = make_float2((float)cos(aB), (float)sin(aB));

    unsigned ph = 0;
    for (int c = 0; c < 4; ++c) {                       // 4 chunks x 16 images
        float2* scr = scratch + ((size_t)(c & 1) << 22);   // 32MB double-buffer slots
#pragma unroll 1
        for (int it = 0; it < 2; ++it) {                // 1024 row tasks / 512 blocks
            const int task = (it<<9) + (int)blockIdx.x;
            row_task(gen, tgt, scr, (c<<4) + (task>>6), task>>6, task&63,
                     SBUF, tid, wave, lane, wA, wB);
        }
        grid_barrier(bar, (++ph) * NBLK);               // rows(c) -> cols(c)
#pragma unroll 1
        for (int it = 0; it < 2; ++it) {                // 1024 col tasks / 512 blocks
            const int task = (it<<9) + (int)blockIdx.x;
            col_task(scr, accum, (c<<4) + (task>>6), task>>6, task&63,
                     SBUF, RED, tid, wave, lane, wA, wB);
        }
        // no trailing barrier: rows(c+1) write the other scratch slot; barrier (c+1)
        // gates cols(c+1) and (transitively) rows(c+2)'s slot reuse.
    }
    grid_barrier(bar, (++ph) * NBLK);                   // all atomics done
    if (blockIdx.x == 0 && tid < 64) {
        const double g  = accum[tid];
        const double t2 = accum[64 + tid];
        double d = fabs(g - t2) * (1.0 / 245760.0);
#pragma unroll
        for (int off = 32; off; off >>= 1) d += __shfl_down(d, off);
        if (tid == 0) out[0] = (float)(d * (1.0 / 64.0));   // WEIGHT = 1.0
    }
}

extern "C" void kernel_launch(void* const* d_in, const int* in_sizes, int n_in,
                              void* d_out, int out_size, void* d_ws, size_t ws_size,
                              hipStream_t stream) {
    (void)in_sizes; (void)n_in; (void)out_size; (void)ws_size;
    const float* gen = (const float*)d_in[0];
    const float* tgt = (const float*)d_in[1];
    float*    out     = (float*)d_out;
    double*   accum   = (double*)d_ws;
    unsigned* bar     = (unsigned*)((char*)d_ws + 1024);
    float2*   scratch = (float2*)((char*)d_ws + 4096);

    hipMemsetAsync(d_ws, 0, 4096, stream);   // zero accum + barrier counter
    hipLaunchKernelGGL(hfs_fused, dim3(NBLK), dim3(512), 0, stream,
                       gen, tgt, scratch, accum, bar, out);
}

// Round 6
// 767.625 us; speedup vs baseline: 1.1271x; 1.1271x over previous
//
#include <hip/hip_runtime.h>
#include <math.h>

#ifndef M_PI
#define M_PI 3.14159265358979323846
#endif

#define NBLK 512   // 512 blocks x 512 thr = 2 blocks/CU, all co-resident (grid barrier safe)

// B=64, C=3, H=W=512.
// Loss = mean_b | mean_hf(log10 PSD(gen_b)) - mean_hf(log10 PSD(tgt_b)) |
// hf region (unshifted freq): EXCLUDED iff ky and kx both in [0,64)u[448,512); count=245760.
// For col spectrum position ky = cc + 8dd + 64e: ky<64 <=> e==0, ky>=448 <=> e==7 (uniform!).
//
// Single persistent kernel, whole-problem phases:
//   rows (4096 tasks, pipelined prefetch) -> grid barrier -> cols (4096 tasks, pipelined)
//   -> grid barrier -> finalize.
// fft512_reg uses WAVE-PRIVATE LDS: no __syncthreads inside (only per-wave lgkmcnt,
// compiler-inserted). Block barriers only at cross-wave staging (2 per task).
//
// scratch layout [img][rg][col][j] (rg=r>>3, j=r&7): row blocks write contiguous 32KB
// tiles (no partial-line RMW); col reads are 64B clusters (L3-served).
// storage col encodes kx: col(kx) = 64*(kx>>6) + 8*(kx&7) + ((kx>>3)&7).
//
// ws: [0,1024) double accum[128]; [1024,1028) unsigned bar; [4096, +128MB) scratch.

__device__ __forceinline__ float2 cmulf(float2 a, float2 b) {
    return make_float2(fmaf(a.x, b.x, -(a.y * b.y)), fmaf(a.x, b.y, a.y * b.x));
}
__device__ __forceinline__ float2 caddf(float2 a, float2 b){ return make_float2(a.x+b.x, a.y+b.y); }
__device__ __forceinline__ float2 csubf(float2 a, float2 b){ return make_float2(a.x-b.x, a.y-b.y); }

// natural-order 8-point DFT: v[k] <- sum_a v[a] W_8^{ak}
__device__ __forceinline__ void dft8(float2 v[8]) {
    const float S = 0.70710678118654752440f;
    float2 a0=caddf(v[0],v[4]), a1=caddf(v[1],v[5]), a2=caddf(v[2],v[6]), a3=caddf(v[3],v[7]);
    float2 b0=csubf(v[0],v[4]);
    float2 t1=csubf(v[1],v[5]);
    float2 t2=csubf(v[2],v[6]);
    float2 t3=csubf(v[3],v[7]);
    float2 b1=make_float2(S*(t1.x+t1.y), S*(t1.y-t1.x));   // *(S,-S) = W8^1
    float2 b2=make_float2(t2.y, -t2.x);                    // *(-i)   = W8^2
    float2 b3=make_float2(S*(t3.y-t3.x), -S*(t3.x+t3.y));  // *(-S,-S)= W8^3
    float2 c0=caddf(a0,a2), c1=caddf(a1,a3), c2=csubf(a0,a2);
    float2 u3=csubf(a1,a3); float2 c3=make_float2(u3.y,-u3.x);
    float2 d0=caddf(b0,b2), d1=caddf(b1,b3), d2=csubf(b0,b2);
    float2 w3=csubf(b1,b3); float2 d3=make_float2(w3.y,-w3.x);
    v[0]=caddf(c0,c1); v[4]=csubf(c0,c1);
    v[2]=caddf(c2,c3); v[6]=csubf(c2,c3);
    v[1]=caddf(d0,d1); v[5]=csubf(d0,d1);
    v[3]=caddf(d2,d3); v[7]=csubf(d2,d3);
}

__device__ __forceinline__ void twchain(float2 v[8], float2 w) {
    float2 t = w;
#pragma unroll
    for (int c = 1; c < 8; ++c) {
        v[c] = cmulf(v[c], t);
        if (c < 7) t = cmulf(t, w);
    }
}

// Per-wave 512-pt FFT (512=8*8*8). In: v[a]=x[64a+lane]. Out: lane L, reg e = X[(L>>3)+8*(L&7)+64e].
// W = wave-PRIVATE 512-float2 LDS region -> NO block barriers needed (per-wave lgkmcnt only).
// T1: rotation swizzle (m+2c)&63; T2: XOR swizzle (8d+(p^d)+2c)&63. Both bijective, bank-floor.
__device__ __forceinline__ void fft512_reg(float2 v[8], float2* __restrict__ W,
                                           float2 wA, float2 wB, int lane) {
    dft8(v);
    twchain(v, wA);
#pragma unroll
    for (int c = 0; c < 8; ++c) W[(c<<6) + ((lane + 2*c)&63)] = v[c];
    {
        const int c = lane>>3, p = lane&7, base = c<<6, off = p + 2*c;
#pragma unroll
        for (int bb = 0; bb < 8; ++bb) v[bb] = W[base + (((bb<<3) + off)&63)];
    }
    dft8(v);
    twchain(v, wB);
    {
        const int c = lane>>3, p = lane&7, base = c<<6, r2 = 2*c;
#pragma unroll
        for (int d = 0; d < 8; ++d) W[base + (((d<<3) + (p^d) + r2)&63)] = v[d];
    }
    {
        const int c = lane>>3, d = lane&7, base = c<<6, off = (d<<3) + 2*c;
#pragma unroll
        for (int p = 0; p < 8; ++p) v[p] = W[base + ((off + (p^d))&63)];
    }
    dft8(v);
}

// Monotonic-counter grid barrier (all NBLK blocks co-resident). Proven in R5.
__device__ __forceinline__ void grid_barrier(unsigned* bar, unsigned target) {
    __syncthreads();
    if (threadIdx.x == 0) {
        __builtin_amdgcn_fence(__ATOMIC_RELEASE, "agent");
        __hip_atomic_fetch_add(bar, 1u, __ATOMIC_RELAXED, __HIP_MEMORY_SCOPE_AGENT);
        while (__hip_atomic_load(bar, __ATOMIC_RELAXED, __HIP_MEMORY_SCOPE_AGENT) < target)
            __builtin_amdgcn_s_sleep(8);
        __builtin_amdgcn_fence(__ATOMIC_ACQUIRE, "agent");
    }
    __syncthreads();
}

__device__ __forceinline__ void row_load(const float* __restrict__ gen,
        const float* __restrict__ tgt, int b, int r, int lane,
        float rG[8][3], float rT[8][3]) {
    const size_t rowoff = ((size_t)b * 1536 + r) * 512;
    const float* gR = gen + rowoff; const float* gG = gR + 262144; const float* gB = gG + 262144;
    const float* tR = tgt + rowoff; const float* tG = tR + 262144; const float* tB = tG + 262144;
#pragma unroll
    for (int a = 0; a < 8; ++a) {
        const int idx = (a<<6) + lane;
        rG[a][0]=gR[idx]; rG[a][1]=gG[idx]; rG[a][2]=gB[idx];
        rT[a][0]=tR[idx]; rT[a][1]=tG[idx]; rT[a][2]=tB[idx];
    }
}

// col source addr for spectrum row r of column col: (img<<18) + ((r>>3)<<12) + (col<<3) + (r&7)
__device__ __forceinline__ void col_load(const float2* __restrict__ scr,
        int img, int col, int lane, float2 pv[8]) {
    const float2* base = scr + ((size_t)img<<18) + ((size_t)(lane>>3)<<12) + (col<<3) + (lane&7);
#pragma unroll
    for (int a = 0; a < 8; ++a) pv[a] = base[(size_t)a<<15];   // r = 64a+lane
}

__global__ __launch_bounds__(512, 4)
void hfs_fused(const float* __restrict__ gen, const float* __restrict__ tgt,
               float2* __restrict__ scratch, double* __restrict__ accum,
               unsigned* __restrict__ bar, float* __restrict__ out) {
    __shared__ float2 SBUF[8 * 512];   // 32 KB, wave-private 512-regions
    __shared__ double RED[16];
    const int tid = threadIdx.x, wave = tid>>6, lane = tid&63;
    float2* W = SBUF + (wave<<9);

    const double aA = -2.0 * M_PI * (double)lane / 512.0;
    const double aB = -2.0 * M_PI * (double)((lane&7)<<3) / 512.0;
    const float2 wA = make_float2((float)cos(aA), (float)sin(aA));
    const float2 wB = make_float2((float)cos(aB), (float)sin(aB));

    // ---------------- row phase: 4096 tasks, prefetch-pipelined ----------------
    {
        int task = (int)blockIdx.x;
        float rG[8][3], rT[8][3];
        row_load(gen, tgt, task>>6, ((task&63)<<3) + wave, lane, rG, rT);
#pragma unroll 1
        for (int it = 0; it < 8; ++it) {
            const int img = task>>6, rg = task&63;
            float2 v[8];
#pragma unroll
            for (int a = 0; a < 8; ++a) {
                v[a] = make_float2(
                    fmaf(0.299f, rG[a][0], fmaf(0.587f, rG[a][1], fmaf(0.114f, rG[a][2], 1.0f)))*0.5f,
                    fmaf(0.299f, rT[a][0], fmaf(0.587f, rT[a][1], fmaf(0.114f, rT[a][2], 1.0f)))*0.5f);
            }
            if (it < 7) {   // prefetch next task while FFT runs
                const int nt = task + NBLK;
                row_load(gen, tgt, nt>>6, ((nt&63)<<3) + wave, lane, rG, rT);
            }
            fft512_reg(v, W, wA, wB, lane);
            // stage for contiguous stores: SBUF[w*512 + ((colpos + 8w)&511)] = (colpos, row j=w)
#pragma unroll
            for (int e = 0; e < 8; ++e) {
                const int colpos = (e<<6) + lane;
                W[(colpos + (wave<<3)) & 511] = v[e];
            }
            __syncthreads();
            // store block-owned 32KB tile scratch[img][rg][col][j], fully contiguous
            float2* dst = scratch + ((size_t)img<<18) + ((size_t)rg<<12);
#pragma unroll
            for (int s2 = 0; s2 < 8; ++s2) {
                const int e = (s2<<9) + tid;          // e = col*8 + j
                const int col = e>>3, j = e&7;
                dst[e] = SBUF[(j<<9) + ((col + (j<<3)) & 511)];
            }
            __syncthreads();
            task += NBLK;
        }
    }

    grid_barrier(bar, NBLK);   // rows -> cols (agent fences: cross-XCD scratch visibility)

    // ---------------- col phase: 4096 tasks, prefetch-pipelined ----------------
    {
        const int unit = wave>>1, w = wave&1;
        int task = (int)blockIdx.x;
        float2 pv[8];
        {
            const int t0 = ((task&63)<<2) + unit;
            const int kx0 = (t0==0) ? (w<<8) : (w ? 512-t0 : t0);
            col_load(scratch, task>>6, ((kx0>>6)<<6) + ((kx0&7)<<3) + ((kx0>>3)&7), lane, pv);
        }
#pragma unroll 1
        for (int it = 0; it < 8; ++it) {
            const int b = task>>6, tq = task&63;
            const int t = (tq<<2) + unit;
            const int kx = (t==0) ? (w<<8) : (w ? 512-t : t);
            float2 v[8];
#pragma unroll
            for (int a = 0; a < 8; ++a) v[a] = pv[a];
            if (it < 7) {   // prefetch next task
                const int nt = task + NBLK;
                const int t2 = ((nt&63)<<2) + unit;
                const int kx2 = (t2==0) ? (w<<8) : (w ? 512-t2 : t2);
                col_load(scratch, nt>>6, ((kx2>>6)<<6) + ((kx2&7)<<3) + ((kx2>>3)&7), lane, pv);
            }
            fft512_reg(v, W, wA, wB, lane);
            // publish own spectrum in natural-ky order
            const int cc = lane>>3, dd = lane&7;
#pragma unroll
            for (int e = 0; e < 8; ++e) W[cc + (dd<<3) + (e<<6)] = v[e];
            __syncthreads();
            const float2* pbuf = (t==0) ? W : (SBUF + (unit<<10) + ((1-w)<<9));
            const bool kxin = (kx < 64) || (kx >= 448);
            double sg = 0.0, st = 0.0;
#pragma unroll
            for (int e = 0; e < 8; ++e) {
                if (kxin && (e == 0 || e == 7)) continue;   // ky in excluded band (uniform!)
                const int ky = cc + (dd<<3) + (e<<6);
                const float2 F1 = v[e];
                const float2 F2 = pbuf[(512 - ky) & 511];   // Z[-ky][-kx]
                const float ar = 0.5f*(F1.x + F2.x), ai = 0.5f*(F1.y - F2.y);   // gen
                const float br = 0.5f*(F1.y + F2.y), bi = 0.5f*(F2.x - F1.x);   // tgt
                const float pg = fmaf(ar, ar, ai*ai) + 1e-10f;
                const float pt = fmaf(br, br, bi*bi) + 1e-10f;
                sg += (double)log10f(pg);
                st += (double)log10f(pt);
            }
#pragma unroll
            for (int off = 32; off; off >>= 1) {
                sg += __shfl_down(sg, off);
                st += __shfl_down(st, off);
            }
            if (lane == 0) { RED[wave] = sg; RED[8 + wave] = st; }
            __syncthreads();
            if (tid == 0) {
                double SG = 0.0, ST = 0.0;
#pragma unroll
                for (int i = 0; i < 8; ++i) { SG += RED[i]; ST += RED[8+i]; }
                atomicAdd(&accum[b], SG);
                atomicAdd(&accum[64 + b], ST);
            }
            task += NBLK;
        }
    }

    grid_barrier(bar, 2u * NBLK);   // all atomics visible
    if (blockIdx.x == 0 && tid < 64) {
        double d = fabs(accum[tid] - accum[64 + tid]) * (1.0 / 245760.0);
#pragma unroll
        for (int off = 32; off; off >>= 1) d += __shfl_down(d, off);
        if (tid == 0) out[0] = (float)(d * (1.0 / 64.0));   // WEIGHT = 1.0
    }
}

extern "C" void kernel_launch(void* const* d_in, const int* in_sizes, int n_in,
                              void* d_out, int out_size, void* d_ws, size_t ws_size,
                              hipStream_t stream) {
    (void)in_sizes; (void)n_in; (void)out_size; (void)ws_size;
    const float* gen = (const float*)d_in[0];
    const float* tgt = (const float*)d_in[1];
    float*    out     = (float*)d_out;
    double*   accum   = (double*)d_ws;
    unsigned* bar     = (unsigned*)((char*)d_ws + 1024);
    float2*   scratch = (float2*)((char*)d_ws + 4096);

    hipMemsetAsync(d_ws, 0, 4096, stream);   // zero accum + barrier counter
    hipLaunchKernelGGL(hfs_fused, dim3(NBLK), dim3(512), 0, stream,
                       gen, tgt, scratch, accum, bar, out);
}